// Round 13
// baseline (378.192 us; speedup 1.0000x reference)
//
#include <hip/hip_runtime.h>

// SwitchTransformers sparse MLP (top-1 MoE), MI355X/gfx950.
// Round 13: direct-fp32-weight GEMMs with conflict-free B staging
// (strided-col dword loads, BSTR=32, 16B-slot XOR sigma(c)=(c^(c>>2))&3 ->
// 2-way uniform banks on both ds_write_b64 and ds_read_b128) and BM=256
// retile (256x128 tile, 4 waves, 48KB LDS, 3 blocks/CU; halves B re-read).
// GEMM2 split-K=4. Router/scan/copy/reduce as before (TM=256 re-dim).

typedef __attribute__((ext_vector_type(4))) float f32x4;
typedef __attribute__((ext_vector_type(8))) short short8;
typedef unsigned short ushort_t;
typedef unsigned int uint32;

#define DEVFN static __device__ __forceinline__
#define MFMA __builtin_amdgcn_mfma_f32_16x16x32_bf16

constexpr int NTOK = 4096;
constexpr int DM   = 768;
constexpr int DF   = 3072;
constexpr int NE   = 8;
constexpr int TM   = 256;                  // row-tile granule (BM)
constexpr int MAXTILES = NTOK / TM + NE;   // 24
constexpr int MAXR  = MAXTILES * TM;       // 6144
constexpr int BK    = 32;
constexpr int KS    = 4;                   // GEMM2 split-K

// meta ints: [8..15] segStart, [16..23] seg_end, [24] nTiles,
// [64..87] tileExpert, [128..151] tileRow
DEVFN ushort_t f2bf(float f) {           // RNE (activations)
  uint32 u = __float_as_uint(f);
  u += 0x7fffu + ((u >> 16) & 1u);
  return (ushort_t)(u >> 16);
}
DEVFN float bf2f(ushort_t u) { return __uint_as_float((uint32)u << 16); }
DEVFN uint32 pkbf(float a, float b) {    // truncating pack: bf16(a)|bf16(b)<<16
  return (__float_as_uint(b) & 0xffff0000u) | (__float_as_uint(a) >> 16);
}

DEVFN void gl16(const void* g, void* l) {   // 16B/lane direct-to-LDS
  __builtin_amdgcn_global_load_lds(
      (const __attribute__((address_space(1))) void*)g,
      (__attribute__((address_space(3))) void*)l, 16, 0, 0);
}

// One wave per token: fp64 logits (argmax robustness), fp32 softmax
// computed redundantly on all lanes (no divergent fp64 exp, no atomics).
__global__ __launch_bounds__(256) void k_router(
    const float* __restrict__ X, const float* __restrict__ Wr,
    float* __restrict__ out_logits, float* __restrict__ out_idx,
    int* __restrict__ expert_of, float* __restrict__ prob) {
  int wid = threadIdx.x >> 6, lane = threadIdx.x & 63;
  int t = blockIdx.x * 4 + wid;
  const float* xrow = X + (size_t)t * DM;
  double acc[NE];
#pragma unroll
  for (int e = 0; e < NE; e++) acc[e] = 0.0;
  for (int d0 = 0; d0 < DM; d0 += 64) {
    int d = d0 + lane;
    float x = xrow[d];
    const float4* w4 = (const float4*)(Wr + (size_t)d * NE);
    float4 wa = w4[0], wb = w4[1];
    acc[0] += (double)x * wa.x; acc[1] += (double)x * wa.y;
    acc[2] += (double)x * wa.z; acc[3] += (double)x * wa.w;
    acc[4] += (double)x * wb.x; acc[5] += (double)x * wb.y;
    acc[6] += (double)x * wb.z; acc[7] += (double)x * wb.w;
  }
#pragma unroll
  for (int e = 0; e < NE; e++) {
#pragma unroll
    for (int s = 32; s > 0; s >>= 1) acc[e] += __shfl_xor(acc[e], s);
  }
#pragma unroll
  for (int e = 0; e < NE; e++)
    if (lane == e) out_logits[(size_t)t * NE + e] = (float)acc[e];
  double m = acc[0]; int idx = 0;
#pragma unroll
  for (int e = 1; e < NE; e++) if (acc[e] > m) { m = acc[e]; idx = e; }
  float s = 0.f;
#pragma unroll
  for (int e = 0; e < NE; e++) s += expf((float)(acc[e] - m));
  if (lane == 0) {
    out_idx[t] = (float)idx;
    expert_of[t] = idx;
    prob[t] = 1.f / s;
  }
}

// Single-block scan: per-group counts, per-expert exclusive scan, padded
// segment layout + tile table, stable-order scatter. Deterministic.
__global__ __launch_bounds__(64) void k_scan(
    const int* __restrict__ expert_of, const float* __restrict__ prob,
    int* __restrict__ meta, int* __restrict__ perm,
    float* __restrict__ prob_g) {
  __shared__ int exl[NTOK];
  int lane = threadIdx.x;
  const int4* src = (const int4*)expert_of;
  int4* dst = (int4*)exl;
#pragma unroll
  for (int j = 0; j < NTOK / 4 / 64; j++) dst[j * 64 + lane] = src[j * 64 + lane];
  __syncthreads();
  int cnt[NE];
#pragma unroll
  for (int e = 0; e < NE; e++) cnt[e] = 0;
  for (int j = 0; j < 64; j++) {
    int ex = exl[lane * 64 + j];
#pragma unroll
    for (int e = 0; e < NE; e++) cnt[e] += (ex == e);
  }
  int base[NE], tot[NE];
#pragma unroll
  for (int e = 0; e < NE; e++) {
    int inc = cnt[e];
#pragma unroll
    for (int s = 1; s < 64; s <<= 1) {
      int o = __shfl_up(inc, s);
      if (lane >= s) inc += o;
    }
    base[e] = inc - cnt[e];
    tot[e] = __shfl(inc, 63);
  }
  int segStart[NE];
  int pos = 0, nt = 0;
#pragma unroll
  for (int e = 0; e < NE; e++) {
    segStart[e] = pos;
    int tiles = (tot[e] + TM - 1) / TM;
    if (lane == 0) {
      meta[8 + e] = pos;
      meta[16 + e] = pos + tot[e];
      for (int i = 0; i < tiles; i++) {
        meta[64 + nt + i] = e;
        meta[128 + nt + i] = pos + i * TM;
      }
    }
    nt += tiles;
    pos += tiles * TM;
  }
  if (lane == 0) meta[24] = nt;
  int cum[NE];
#pragma unroll
  for (int e = 0; e < NE; e++) cum[e] = segStart[e] + base[e];
  for (int j = 0; j < 64; j++) {
    int t = lane * 64 + j;
    int ex = exl[lane * 64 + j];
    int p = 0;
#pragma unroll
    for (int e = 0; e < NE; e++) p += (ex == e) ? cum[e] : 0;
#pragma unroll
    for (int e = 0; e < NE; e++) cum[e] += (ex == e);
    perm[p] = t;
    prob_g[p] = prob[t];
  }
}

// Destination-indexed gather: Xg[r] = bf16(X[perm[r]]) for valid rows.
__global__ __launch_bounds__(256) void k_copy(
    const float* __restrict__ X, const int* __restrict__ meta,
    const int* __restrict__ perm, ushort_t* __restrict__ Xg) {
  int bt = blockIdx.y;
  if (bt >= meta[24]) return;
  int e = meta[64 + bt], row0 = meta[128 + bt], segEnd = meta[16 + e];
  int wid = threadIdx.x >> 6, lane = threadIdx.x & 63;
  int r = row0 + blockIdx.x * 4 + wid;
  if (r >= segEnd) return;
  int tok = perm[r];
  const float2* s2 = (const float2*)(X + (size_t)tok * DM);
  uint32* d2 = (uint32*)(Xg + (size_t)r * DM);
#pragma unroll
  for (int i = 0; i < DM / 128; i++) {
    float2 v = s2[i * 64 + lane];
    d2[i * 64 + lane] = (uint32)f2bf(v.x) | ((uint32)f2bf(v.y) << 16);
  }
}

// ---------------------------------------------------------------------------
// 4-wave 256x128 GEMM, BK=32, LDS double-buffer, ONE barrier per K-step.
// A: bf16 [rows][KTOT] via global_load_lds (XOR-swizzled source, linear LDS).
// B: fp32 [KTOT][NB] reg-staged; thread (kq=tid>>5, nc=tid&31) covers
//    k-quad kq (4 k's) x cols {nc, nc+32, nc+64, nc+96} (strided -> sigma
//    varies per lane). Pack to bf16 k-quads, ds_write_b64 into BSTR=32
//    layout with phys 16B-slot = (kq>>1) ^ sigma(c), sigma(c)=(c^(c>>2))&3
//    (verified: every bank hit exactly 2x on write AND read -> free).
// Per-wave output 128x64 (2Mx2N waves), acc[8][4], 32 MFMA + {8 b128 A,
// 4 b128 B} reads per wave-K-step.
// Grid: y = row-tile (slow, live-compact). FIRST: x = N-panel.
// !FIRST: x = panel*KSPLIT + z, koff = z*(KTOT/KSPLIT).
// ---------------------------------------------------------------------------
template <int KTOT, int NB, int KSPLIT, bool FIRST>
__global__ __launch_bounds__(256, 3) void k_gemm8(
    const ushort_t* __restrict__ A, const float* __restrict__ Bw,
    const int* __restrict__ meta, ushort_t* __restrict__ Obf) {
  constexpr int NKTT = KTOT / KSPLIT / BK;   // 24
  __shared__ short A_lds[2][256 * BK];       // 32 KB
  __shared__ short B_lds[2][128 * BK];       // 16 KB

  int bt = blockIdx.y;
  if (bt >= meta[24]) return;      // uniform exit before any barrier
  int e    = meta[64 + bt];
  int row0 = meta[128 + bt];
  int n0, koff, z;
  if constexpr (FIRST) {
    n0 = blockIdx.x * 128; koff = 0; z = 0;
  } else {
    n0 = (blockIdx.x / KSPLIT) * 128; z = blockIdx.x % KSPLIT;
    koff = z * (KTOT / KSPLIT);
  }

  int tid = threadIdx.x, lane = tid & 63, w = tid >> 6;
  int wr = w >> 1, wc = w & 1;

  // ---- A staging (global_load_lds, pre-swizzled source, linear dest) ----
  // row = w*16 + (lane>>2) (+64/128/192); (row>>1)&3 == (lane>>3)&3.
  int srcSlot = (lane & 3) ^ ((lane >> 3) & 3);
  const ushort_t* aS = A + (size_t)(row0 + (tid >> 2)) * KTOT + koff + srcSlot * 8;
  int dstOff = w * 512;

#define STAGE_A(buf, kt)                                                      \
  do {                                                                        \
    const ushort_t* a0 = aS + (size_t)(kt) * BK;                              \
    gl16(a0,                        &A_lds[buf][dstOff]);                     \
    gl16(a0 + (size_t)64 * KTOT,    &A_lds[buf][dstOff + 2048]);              \
    gl16(a0 + (size_t)128 * KTOT,   &A_lds[buf][dstOff + 4096]);              \
    gl16(a0 + (size_t)192 * KTOT,   &A_lds[buf][dstOff + 6144]);              \
  } while (0)

  // ---- B staging: kq = tid>>5 (8 k-quads), nc = tid&31, cols nc+32*nn ----
  int kq = tid >> 5, nc = tid & 31;
  const float* bS = Bw + (size_t)e * KTOT * NB + ((size_t)koff + kq * 4) * NB
                    + n0 + nc;
  float bv[4][4];   // [kk][nn]

#define LOAD_B(kt)                                                            \
  do {                                                                        \
    const float* b0 = bS + (size_t)(kt) * BK * NB;                            \
    _Pragma("unroll") for (int kk = 0; kk < 4; kk++)                          \
      _Pragma("unroll") for (int nn = 0; nn < 4; nn++)                        \
        bv[kk][nn] = b0[(size_t)kk * NB + nn * 32];                           \
  } while (0)

#define WRITE_B(buf)                                                          \
  do {                                                                        \
    _Pragma("unroll") for (int nn = 0; nn < 4; nn++) {                        \
      int c = nc + 32 * nn;                                                   \
      int sg = (c ^ (c >> 2)) & 3;                                            \
      int ad = c * BK + (((kq >> 1) ^ sg) << 3) + ((kq & 1) << 2);            \
      uint32 w0 = pkbf(bv[0][nn], bv[1][nn]);                                 \
      uint32 w1 = pkbf(bv[2][nn], bv[3][nn]);                                 \
      *(uint2*)&B_lds[buf][ad] = (uint2){w0, w1};                             \
    }                                                                         \
  } while (0)

  // ---- fragment read offsets ----
  int g = lane >> 4;
  int kslotRd = (g ^ ((lane >> 1) & 3)) * 8;   // A (swizzled)
  int aOff[8], bOff[4];
#pragma unroll
  for (int m = 0; m < 8; m++)
    aOff[m] = (wr * 128 + m * 16 + (lane & 15)) * BK + kslotRd;
#pragma unroll
  for (int n = 0; n < 4; n++) {
    int col = wc * 64 + n * 16 + (lane & 15);
    int sg = (col ^ (col >> 2)) & 3;
    bOff[n] = col * BK + ((g ^ sg) << 3);
  }

  f32x4 acc[8][4];
#pragma unroll
  for (int m = 0; m < 8; m++)
#pragma unroll
    for (int n = 0; n < 4; n++) acc[m][n] = (f32x4){0.f, 0.f, 0.f, 0.f};

  // prologue: tile 0 into buf 0
  LOAD_B(0);
  STAGE_A(0, 0);
  WRITE_B(0);
  __syncthreads();

#pragma unroll 2
  for (int t = 0; t < NKTT; ++t) {
    int cur = t & 1;
    if (t + 1 < NKTT) {
      LOAD_B(t + 1);               // issue early: latency under compute
      STAGE_A(cur ^ 1, t + 1);
    }
    const short* aB = A_lds[cur];
    const short* bB = B_lds[cur];
    short8 af[8], bf[4];
#pragma unroll
    for (int m = 0; m < 8; m++) af[m] = *(const short8*)&aB[aOff[m]];
#pragma unroll
    for (int n = 0; n < 4; n++) bf[n] = *(const short8*)&bB[bOff[n]];
    __builtin_amdgcn_s_setprio(1);
#pragma unroll
    for (int m = 0; m < 8; m++)
#pragma unroll
      for (int n = 0; n < 4; n++)
        acc[m][n] = MFMA(af[m], bf[n], acc[m][n], 0, 0, 0);
    __builtin_amdgcn_s_setprio(0);
    if (t + 1 < NKTT) WRITE_B(cur ^ 1);   // write late (after MFMAs)
    __syncthreads();                       // drains gl16 + ds writes
  }
#undef STAGE_A
#undef LOAD_B
#undef WRITE_B

  // C/D: col = lane&15, row = (lane>>4)*4 + r
  ushort_t* dst = FIRST ? Obf : Obf + (size_t)z * MAXR * NB;
#pragma unroll
  for (int m = 0; m < 8; m++) {
    int rowb = row0 + wr * 128 + m * 16 + (lane >> 4) * 4;
#pragma unroll
    for (int n = 0; n < 4; n++) {
      int col = n0 + wc * 64 + n * 16 + (lane & 15);
#pragma unroll
      for (int r = 0; r < 4; r++) {
        float v = acc[m][n][r];
        if (FIRST) v = v > 0.f ? v : 0.f;
        dst[(size_t)(rowb + r) * NB + col] = f2bf(v);
      }
    }
  }
}

// Reduce split-K partials, scale by prob, scatter to token rows.
__global__ __launch_bounds__(256) void k_reduce(
    const ushort_t* __restrict__ P, const int* __restrict__ meta,
    const int* __restrict__ perm, const float* __restrict__ prob_g,
    float* __restrict__ out) {
  int bt = blockIdx.y;
  if (bt >= meta[24]) return;
  int e = meta[64 + bt], row0 = meta[128 + bt], segEnd = meta[16 + e];
  int c0 = blockIdx.x * 64;
  int t = threadIdx.x;
  int col = c0 + (t & 7) * 8;
#pragma unroll
  for (int i = 0; i < 8; i++) {
    int r = row0 + (t >> 3) + i * 32;
    if (r >= segEnd) continue;
    int tok = perm[r];
    float p = prob_g[r];
    float s[8];
#pragma unroll
    for (int j = 0; j < 8; j++) s[j] = 0.f;
#pragma unroll
    for (int z = 0; z < KS; z++) {
      short8 v = *(const short8*)&P[((size_t)z * MAXR + r) * DM + col];
#pragma unroll
      for (int j = 0; j < 8; j++) s[j] += bf2f((ushort_t)v[j]);
    }
    float4 o0 = {p * s[0], p * s[1], p * s[2], p * s[3]};
    float4 o1 = {p * s[4], p * s[5], p * s[6], p * s[7]};
    *(float4*)&out[(size_t)tok * DM + col] = o0;
    *(float4*)&out[(size_t)tok * DM + col + 4] = o1;
  }
}

extern "C" void kernel_launch(void* const* d_in, const int* in_sizes, int n_in,
                              void* d_out, int out_size, void* d_ws, size_t ws_size,
                              hipStream_t stream) {
  const float* X  = (const float*)d_in[0];
  const float* Wr = (const float*)d_in[1];
  const float* wi = (const float*)d_in[2];   // [8][768][3072] fp32
  const float* wo = (const float*)d_in[3];   // [8][3072][768] fp32

  float* out        = (float*)d_out;
  float* out_logits = out + (size_t)NTOK * DM;
  float* out_idx    = out_logits + (size_t)NTOK * NE;

  char* w = (char*)d_ws;
  int*      meta      = (int*)w;                    // 4 KiB
  int*      expert_of = (int*)(w + 4096);           // 16 KiB
  float*    prob      = (float*)(w + 20480);        // 16 KiB
  int*      perm      = (int*)(w + 36864);          // 24 KiB
  float*    prob_g    = (float*)(w + 61440);        // 24 KiB
  ushort_t* Xg        = (ushort_t*)(w + 131072);    // 6144*768 bf16 (9.4MB)
  ushort_t* H         = Xg + (size_t)MAXR * DM;     // 6144*3072 bf16 (37.7MB)
  ushort_t* P         = H + (size_t)MAXR * DF;      // 4*6144*768 bf16 (37.7MB)
  // total ws ~ 85 MB

  k_router<<<NTOK / 4, 256, 0, stream>>>(X, Wr, out_logits, out_idx,
                                         expert_of, prob);
  k_scan<<<1, 64, 0, stream>>>(expert_of, prob, meta, perm, prob_g);
  k_copy<<<dim3(TM / 4, MAXTILES), 256, 0, stream>>>(X, meta, perm, Xg);
  k_gemm8<DM, DF, 1, true><<<dim3(DF / 128, MAXTILES), 256, 0, stream>>>(
      Xg, wi, meta, H);
  k_gemm8<DF, DM, KS, false><<<dim3((DM / 128) * KS, MAXTILES), 256, 0, stream>>>(
      H, wo, meta, P);
  k_reduce<<<dim3(DM / 64, MAXTILES), 256, 0, stream>>>(P, meta, perm, prob_g, out);
}

// Round 14
// 139.067 us; speedup vs baseline: 2.7195x; 2.7195x over previous
//
#include <hip/hip_runtime.h>

// SwitchTransformers sparse MLP (top-1 MoE), MI355X/gfx950.
// Round 14: R12 frame (BM=128, 4 waves, acc[4][4] -> no spill; R13's BM=256
// spilled acc to scratch: 420MB/dispatch scratch writes) + R13's verified
// conflict-free B staging: strided cols c=nc+32nn (scalar dword loads),
// sigma(c)=(c^(c>>2))&3 16B-slot XOR -> banks balanced 2-way on both
// ds_write_b64 and ds_read_b128. Direct fp32 weights (no convT pass).

typedef __attribute__((ext_vector_type(4))) float f32x4;
typedef __attribute__((ext_vector_type(8))) short short8;
typedef unsigned short ushort_t;
typedef unsigned int uint32;

#define DEVFN static __device__ __forceinline__
#define MFMA __builtin_amdgcn_mfma_f32_16x16x32_bf16

constexpr int NTOK = 4096;
constexpr int DM   = 768;
constexpr int DF   = 3072;
constexpr int NE   = 8;
constexpr int TM   = 128;                  // row-tile granule (BM)
constexpr int MAXTILES = NTOK / TM + NE;   // 40
constexpr int MAXR  = MAXTILES * TM;       // 5120
constexpr int BK    = 32;
constexpr int KS2   = 2;                   // GEMM2 split-K

// meta ints: [8..15] segStart, [16..23] seg_end, [24] nTiles,
// [64..103] tileExpert, [128..167] tileRow
DEVFN ushort_t f2bf(float f) {           // RNE (activations)
  uint32 u = __float_as_uint(f);
  u += 0x7fffu + ((u >> 16) & 1u);
  return (ushort_t)(u >> 16);
}
DEVFN float bf2f(ushort_t u) { return __uint_as_float((uint32)u << 16); }
DEVFN uint32 pkbf(float a, float b) {    // truncating pack: bf16(a)|bf16(b)<<16
  return (__float_as_uint(b) & 0xffff0000u) | (__float_as_uint(a) >> 16);
}

DEVFN void gl16(const void* g, void* l) {   // 16B/lane direct-to-LDS
  __builtin_amdgcn_global_load_lds(
      (const __attribute__((address_space(1))) void*)g,
      (__attribute__((address_space(3))) void*)l, 16, 0, 0);
}

// One wave per token: fp64 logits (argmax robustness), fp32 softmax
// computed redundantly on all lanes (no divergent fp64 exp, no atomics).
__global__ __launch_bounds__(256) void k_router(
    const float* __restrict__ X, const float* __restrict__ Wr,
    float* __restrict__ out_logits, float* __restrict__ out_idx,
    int* __restrict__ expert_of, float* __restrict__ prob) {
  int wid = threadIdx.x >> 6, lane = threadIdx.x & 63;
  int t = blockIdx.x * 4 + wid;
  const float* xrow = X + (size_t)t * DM;
  double acc[NE];
#pragma unroll
  for (int e = 0; e < NE; e++) acc[e] = 0.0;
  for (int d0 = 0; d0 < DM; d0 += 64) {
    int d = d0 + lane;
    float x = xrow[d];
    const float4* w4 = (const float4*)(Wr + (size_t)d * NE);
    float4 wa = w4[0], wb = w4[1];
    acc[0] += (double)x * wa.x; acc[1] += (double)x * wa.y;
    acc[2] += (double)x * wa.z; acc[3] += (double)x * wa.w;
    acc[4] += (double)x * wb.x; acc[5] += (double)x * wb.y;
    acc[6] += (double)x * wb.z; acc[7] += (double)x * wb.w;
  }
#pragma unroll
  for (int e = 0; e < NE; e++) {
#pragma unroll
    for (int s = 32; s > 0; s >>= 1) acc[e] += __shfl_xor(acc[e], s);
  }
#pragma unroll
  for (int e = 0; e < NE; e++)
    if (lane == e) out_logits[(size_t)t * NE + e] = (float)acc[e];
  double m = acc[0]; int idx = 0;
#pragma unroll
  for (int e = 1; e < NE; e++) if (acc[e] > m) { m = acc[e]; idx = e; }
  float s = 0.f;
#pragma unroll
  for (int e = 0; e < NE; e++) s += expf((float)(acc[e] - m));
  if (lane == 0) {
    out_idx[t] = (float)idx;
    expert_of[t] = idx;
    prob[t] = 1.f / s;
  }
}

// Single-block scan: per-group counts, per-expert exclusive scan, padded
// segment layout + tile table, stable-order scatter. Deterministic.
__global__ __launch_bounds__(64) void k_scan(
    const int* __restrict__ expert_of, const float* __restrict__ prob,
    int* __restrict__ meta, int* __restrict__ perm,
    float* __restrict__ prob_g) {
  __shared__ int exl[NTOK];
  int lane = threadIdx.x;
  const int4* src = (const int4*)expert_of;
  int4* dst = (int4*)exl;
#pragma unroll
  for (int j = 0; j < NTOK / 4 / 64; j++) dst[j * 64 + lane] = src[j * 64 + lane];
  __syncthreads();
  int cnt[NE];
#pragma unroll
  for (int e = 0; e < NE; e++) cnt[e] = 0;
  for (int j = 0; j < 64; j++) {
    int ex = exl[lane * 64 + j];
#pragma unroll
    for (int e = 0; e < NE; e++) cnt[e] += (ex == e);
  }
  int base[NE], tot[NE];
#pragma unroll
  for (int e = 0; e < NE; e++) {
    int inc = cnt[e];
#pragma unroll
    for (int s = 1; s < 64; s <<= 1) {
      int o = __shfl_up(inc, s);
      if (lane >= s) inc += o;
    }
    base[e] = inc - cnt[e];
    tot[e] = __shfl(inc, 63);
  }
  int segStart[NE];
  int pos = 0, nt = 0;
#pragma unroll
  for (int e = 0; e < NE; e++) {
    segStart[e] = pos;
    int tiles = (tot[e] + TM - 1) / TM;
    if (lane == 0) {
      meta[8 + e] = pos;
      meta[16 + e] = pos + tot[e];
      for (int i = 0; i < tiles; i++) {
        meta[64 + nt + i] = e;
        meta[128 + nt + i] = pos + i * TM;
      }
    }
    nt += tiles;
    pos += tiles * TM;
  }
  if (lane == 0) meta[24] = nt;
  int cum[NE];
#pragma unroll
  for (int e = 0; e < NE; e++) cum[e] = segStart[e] + base[e];
  for (int j = 0; j < 64; j++) {
    int t = lane * 64 + j;
    int ex = exl[lane * 64 + j];
    int p = 0;
#pragma unroll
    for (int e = 0; e < NE; e++) p += (ex == e) ? cum[e] : 0;
#pragma unroll
    for (int e = 0; e < NE; e++) cum[e] += (ex == e);
    perm[p] = t;
    prob_g[p] = prob[t];
  }
}

// Destination-indexed gather: Xg[r] = bf16(X[perm[r]]) for valid rows.
__global__ __launch_bounds__(256) void k_copy(
    const float* __restrict__ X, const int* __restrict__ meta,
    const int* __restrict__ perm, ushort_t* __restrict__ Xg) {
  int bt = blockIdx.y;
  if (bt >= meta[24]) return;
  int e = meta[64 + bt], row0 = meta[128 + bt], segEnd = meta[16 + e];
  int wid = threadIdx.x >> 6, lane = threadIdx.x & 63;
  int r = row0 + blockIdx.x * 4 + wid;
  if (r >= segEnd) return;
  int tok = perm[r];
  const float2* s2 = (const float2*)(X + (size_t)tok * DM);
  uint32* d2 = (uint32*)(Xg + (size_t)r * DM);
#pragma unroll
  for (int i = 0; i < DM / 128; i++) {
    float2 v = s2[i * 64 + lane];
    d2[i * 64 + lane] = (uint32)f2bf(v.x) | ((uint32)f2bf(v.y) << 16);
  }
}

// ---------------------------------------------------------------------------
// 4-wave 128x128 GEMM, BK=32, LDS double-buffer, ONE barrier per K-step.
// A: bf16 [rows][KTOT] via global_load_lds (XOR-swizzled source, linear LDS).
// B: fp32 [KTOT][NB] reg-staged; thread (kq=tid>>5 -> k=4kq..4kq+3,
//    nc=tid&31) covers cols {nc, nc+32, nc+64, nc+96} (strided so sigma
//    varies per lane). Scalar dword loads (128B/half-wave contiguous).
//    Pack to bf16, ds_write_b64 at phys addr c*32 + ((kq>>1)^sg)*8 +
//    (kq&1)*4, sg(c)=(c^(c>>2))&3. Banks: write 16(c&1)+4(slot^sg) covers
//    all 32 banks 2x per half-wave; read b128 likewise 2x per quarter-wave.
// Per-wave output 64x64 (2Mx2N waves), acc[4][4] (64 AGPR -> no spill).
// Grid: y = row-tile (slow, live-compact). FIRST: x = N-panel.
// !FIRST: x = panel*KSPLIT + z, koff = z*(KTOT/KSPLIT).
// ---------------------------------------------------------------------------
template <int KTOT, int NB, int KSPLIT, bool FIRST>
__global__ __launch_bounds__(256, 3) void k_gemm8(
    const ushort_t* __restrict__ A, const float* __restrict__ Bw,
    const int* __restrict__ meta, ushort_t* __restrict__ Obf) {
  constexpr int NKTT = KTOT / KSPLIT / BK;
  __shared__ short A_lds[2][128 * BK];      // 16 KB
  __shared__ short B_lds[2][128 * BK];      // 16 KB

  int bt = blockIdx.y;
  if (bt >= meta[24]) return;      // uniform exit before any barrier
  int e    = meta[64 + bt];
  int row0 = meta[128 + bt];
  int n0, koff, z;
  if constexpr (FIRST) {
    n0 = blockIdx.x * 128; koff = 0; z = 0;
  } else {
    n0 = (blockIdx.x / KSPLIT) * 128; z = blockIdx.x % KSPLIT;
    koff = z * (KTOT / KSPLIT);
  }

  int tid = threadIdx.x, lane = tid & 63, w = tid >> 6;
  int wr = w >> 1, wc = w & 1;

  // ---- A staging (global_load_lds, pre-swizzled source, linear dest) ----
  int srcSlot = (lane & 3) ^ ((lane >> 3) & 3);
  const ushort_t* aS = A + (size_t)(row0 + (tid >> 2)) * KTOT + koff + srcSlot * 8;
  int dstOff = w * 512;

#define STAGE_A(buf, kt)                                                      \
  do {                                                                        \
    gl16(aS + (size_t)(kt) * BK, &A_lds[buf][dstOff]);                        \
    gl16(aS + (size_t)(kt) * BK + (size_t)64 * KTOT,                          \
         &A_lds[buf][dstOff + 2048]);                                         \
  } while (0)

  // ---- B staging: kq = tid>>5, nc = tid&31, cols nc+32*nn ----
  int kq = tid >> 5, nc = tid & 31;
  const float* bS = Bw + (size_t)e * KTOT * NB + ((size_t)koff + kq * 4) * NB
                    + n0 + nc;
  float bv[4][4];   // [kk][nn]

#define LOAD_B(kt)                                                            \
  do {                                                                        \
    const float* b0 = bS + (size_t)(kt) * BK * NB;                            \
    _Pragma("unroll") for (int kk = 0; kk < 4; kk++)                          \
      _Pragma("unroll") for (int nn = 0; nn < 4; nn++)                        \
        bv[kk][nn] = b0[(size_t)kk * NB + nn * 32];                           \
  } while (0)

#define WRITE_B(buf)                                                          \
  do {                                                                        \
    _Pragma("unroll") for (int nn = 0; nn < 4; nn++) {                        \
      int c = nc + 32 * nn;                                                   \
      int sg = (c ^ (c >> 2)) & 3;                                            \
      int ad = c * BK + (((kq >> 1) ^ sg) << 3) + ((kq & 1) << 2);            \
      uint32 w0 = pkbf(bv[0][nn], bv[1][nn]);                                 \
      uint32 w1 = pkbf(bv[2][nn], bv[3][nn]);                                 \
      *(uint2*)&B_lds[buf][ad] = (uint2){w0, w1};                             \
    }                                                                         \
  } while (0)

  // ---- fragment read offsets ----
  int g = lane >> 4;
  int kslotRd = (g ^ ((lane >> 1) & 3)) * 8;   // A (swizzled)
  int aOff[4], bOff[4];
#pragma unroll
  for (int m = 0; m < 4; m++)
    aOff[m] = (wr * 64 + m * 16 + (lane & 15)) * BK + kslotRd;
#pragma unroll
  for (int n = 0; n < 4; n++) {
    int col = wc * 64 + n * 16 + (lane & 15);
    int sg = (col ^ (col >> 2)) & 3;
    bOff[n] = col * BK + ((g ^ sg) << 3);
  }

  f32x4 acc[4][4];
#pragma unroll
  for (int m = 0; m < 4; m++)
#pragma unroll
    for (int n = 0; n < 4; n++) acc[m][n] = (f32x4){0.f, 0.f, 0.f, 0.f};

  // prologue: tile 0 into buf 0
  LOAD_B(0);
  STAGE_A(0, 0);
  WRITE_B(0);
  __syncthreads();

#pragma unroll 2
  for (int t = 0; t < NKTT; ++t) {
    int cur = t & 1;
    if (t + 1 < NKTT) {
      LOAD_B(t + 1);               // issue early: latency under compute
      STAGE_A(cur ^ 1, t + 1);
    }
    const short* aB = A_lds[cur];
    const short* bB = B_lds[cur];
    short8 af[4], bf[4];
#pragma unroll
    for (int m = 0; m < 4; m++) af[m] = *(const short8*)&aB[aOff[m]];
#pragma unroll
    for (int n = 0; n < 4; n++) bf[n] = *(const short8*)&bB[bOff[n]];
    __builtin_amdgcn_s_setprio(1);
#pragma unroll
    for (int m = 0; m < 4; m++)
#pragma unroll
      for (int n = 0; n < 4; n++)
        acc[m][n] = MFMA(af[m], bf[n], acc[m][n], 0, 0, 0);
    __builtin_amdgcn_s_setprio(0);
    if (t + 1 < NKTT) WRITE_B(cur ^ 1);   // write late (after MFMAs)
    __syncthreads();                       // drains gl16 + ds writes
  }
#undef STAGE_A
#undef LOAD_B
#undef WRITE_B

  // C/D: col = lane&15, row = (lane>>4)*4 + r
  ushort_t* dst = FIRST ? Obf : Obf + (size_t)z * MAXR * NB;
#pragma unroll
  for (int m = 0; m < 4; m++) {
    int rowb = row0 + wr * 64 + m * 16 + (lane >> 4) * 4;
#pragma unroll
    for (int n = 0; n < 4; n++) {
      int col = n0 + wc * 64 + n * 16 + (lane & 15);
#pragma unroll
      for (int r = 0; r < 4; r++) {
        float v = acc[m][n][r];
        if (FIRST) v = v > 0.f ? v : 0.f;
        dst[(size_t)(rowb + r) * NB + col] = f2bf(v);
      }
    }
  }
}

// Reduce split-K partials, scale by prob, scatter to token rows.
__global__ __launch_bounds__(256) void k_reduce(
    const ushort_t* __restrict__ P, const int* __restrict__ meta,
    const int* __restrict__ perm, const float* __restrict__ prob_g,
    float* __restrict__ out) {
  int bt = blockIdx.y;
  if (bt >= meta[24]) return;
  int e = meta[64 + bt], row0 = meta[128 + bt], segEnd = meta[16 + e];
  int c0 = blockIdx.x * 64;
  int t = threadIdx.x;
  int col = c0 + (t & 7) * 8;
#pragma unroll
  for (int i = 0; i < 4; i++) {
    int r = row0 + (t >> 3) + i * 32;
    if (r >= segEnd) continue;
    int tok = perm[r];
    float p = prob_g[r];
    float s[8];
#pragma unroll
    for (int j = 0; j < 8; j++) s[j] = 0.f;
#pragma unroll
    for (int z = 0; z < KS2; z++) {
      short8 v = *(const short8*)&P[((size_t)z * MAXR + r) * DM + col];
#pragma unroll
      for (int j = 0; j < 8; j++) s[j] += bf2f((ushort_t)v[j]);
    }
    float4 o0 = {p * s[0], p * s[1], p * s[2], p * s[3]};
    float4 o1 = {p * s[4], p * s[5], p * s[6], p * s[7]};
    *(float4*)&out[(size_t)tok * DM + col] = o0;
    *(float4*)&out[(size_t)tok * DM + col + 4] = o1;
  }
}

extern "C" void kernel_launch(void* const* d_in, const int* in_sizes, int n_in,
                              void* d_out, int out_size, void* d_ws, size_t ws_size,
                              hipStream_t stream) {
  const float* X  = (const float*)d_in[0];
  const float* Wr = (const float*)d_in[1];
  const float* wi = (const float*)d_in[2];   // [8][768][3072] fp32
  const float* wo = (const float*)d_in[3];   // [8][3072][768] fp32

  float* out        = (float*)d_out;
  float* out_logits = out + (size_t)NTOK * DM;
  float* out_idx    = out_logits + (size_t)NTOK * NE;

  char* w = (char*)d_ws;
  int*      meta      = (int*)w;                    // 4 KiB
  int*      expert_of = (int*)(w + 4096);           // 16 KiB
  float*    prob      = (float*)(w + 20480);        // 16 KiB
  int*      perm      = (int*)(w + 36864);          // 24 KiB
  float*    prob_g    = (float*)(w + 61440);        // 24 KiB
  ushort_t* Xg        = (ushort_t*)(w + 131072);    // 5120*768 bf16 (7.9MB)
  ushort_t* H         = Xg + (size_t)MAXR * DM;     // 5120*3072 bf16 (31.5MB)
  ushort_t* P         = H + (size_t)MAXR * DF;      // 2*5120*768 bf16 (15.7MB)
  // total ws ~ 55 MB

  k_router<<<NTOK / 4, 256, 0, stream>>>(X, Wr, out_logits, out_idx,
                                         expert_of, prob);
  k_scan<<<1, 64, 0, stream>>>(expert_of, prob, meta, perm, prob_g);
  k_copy<<<dim3(TM / 4, MAXTILES), 256, 0, stream>>>(X, meta, perm, Xg);
  k_gemm8<DM, DF, 1, true><<<dim3(DF / 128, MAXTILES), 256, 0, stream>>>(
      Xg, wi, meta, H);
  k_gemm8<DF, DM, KS2, false><<<dim3((DM / 128) * KS2, MAXTILES), 256, 0, stream>>>(
      H, wo, meta, P);
  k_reduce<<<dim3(DM / 64, MAXTILES), 256, 0, stream>>>(P, meta, perm, prob_g, out);
}